// Round 1
// baseline (199.754 us; speedup 1.0000x reference)
//
#include <hip/hip_runtime.h>

#define B_ 8
#define C_ 128
#define N_ 4096
#define SCALE 0.08838834764831845f   // 1/sqrt(128)

typedef __attribute__((ext_vector_type(8))) short short8;   // 8 bf16
typedef __attribute__((ext_vector_type(4))) short short4v;  // 4 bf16
typedef __attribute__((ext_vector_type(4))) float f32x4;    // MFMA C/D

__device__ inline float b2f(unsigned short u) {
    union { unsigned int i; float f; } v; v.i = ((unsigned int)u) << 16; return v.f;
}
__device__ inline unsigned short f2b(float f) {            // RNE bf16 round
    unsigned int x = __float_as_uint(f);
    return (unsigned short)((x + 0x7FFFu + ((x >> 16) & 1u)) >> 16);
}

// async global->LDS, 16B per lane (m97 staging path).
__device__ inline void gld_lds16(const void* g, void* l) {
    __builtin_amdgcn_global_load_lds(
        (const __attribute__((address_space(1))) unsigned int*)g,
        (__attribute__((address_space(3))) unsigned int*)l, 16, 0, 0);
}

// ---------------------------------------------------------------------------
// MFMA QKV projection, R13 restructure: PASS-SPLIT grid.
//  - grid 1536 = 8 batches x 64 tiles x 3 passes; bid&7 = batch (XCD-pinned),
//    p = (bid>>3)>>6 selects q/v/k. Each block: stage X tile, one mfma_pass,
//    one direct epilogue. 3x issue-parallelism vs the serial 3-pass block
//    (qkv was latency-bound at 2 blocks/CU, 42 TF).
//  - Obuf ELIMINATED: k stores directly from C/D regs. Lane holds 4
//    consecutive o (r=0..3) for fixed n; O0&7 in {0,4} so the 4 never cross
//    an 8-block -> one aligned short4 at kTs[n][((O0>>3)^(n&15))*8+(O0&7)].
//    LDS 50KB -> 16KB, one barrier total, no LDS round-trip.
//  - biases loaded as float4 (o base 4-aligned).
// kTs bf16 [b][n][o'] o-blocks ^ (n&15). vS bf16 [b][o][n'] 32-key windows,
// block' ^= (o>>1)&3. q fp32 pre-scaled -> d_out.
// mfma_f32_16x16x32_bf16: A[m=l15][k=quad*8+j]; B[k][n=l15];
// C/D row=quad*4+r, col=l15 (R6-R11 proven).
// ---------------------------------------------------------------------------
__global__ __launch_bounds__(256) void qkv_mfma(
    const float* __restrict__ x,
    const float* __restrict__ Wq, const float* __restrict__ bq,
    const float* __restrict__ Wk, const float* __restrict__ bk,
    const float* __restrict__ Wv, const float* __restrict__ bv,
    float* __restrict__ q, unsigned short* __restrict__ kTs,
    unsigned short* __restrict__ vS)
{
    __shared__ __align__(16) short Xs[64 * 128];    // 16 KB bf16 X^T, swizzled

    const int t    = threadIdx.x;
    const int w    = t >> 6;
    const int lane = t & 63;
    const int l15  = lane & 15;
    const int quad = lane >> 4;

    const int b    = blockIdx.x & 7;             // XCD-pinned batch
    const int rest = blockIdx.x >> 3;            // 0..191
    const int p    = rest >> 6;                  // 0=q, 1=v, 2=k
    const int n0   = (rest & 63) * 64;
    const long base = (long)b * C_ * N_;

    const float* W; const float* bias;
    if (p == 0)      { W = Wq; bias = bq; }
    else if (p == 1) { W = Wv; bias = bv; }
    else             { W = Wk; bias = bk; }

    // ---- W A-frags first (loads in flight under X staging) ----
    short8 af[2][4];
    #pragma unroll
    for (int ot = 0; ot < 2; ++ot) {
        const int o = 32 * w + 16 * ot + l15;
        #pragma unroll
        for (int ks = 0; ks < 4; ++ks) {
            const float4 a0 = *(const float4*)(const void*)(W + o * C_ + ks * 32 + quad * 8);
            const float4 a1 = *(const float4*)(const void*)(W + o * C_ + ks * 32 + quad * 8 + 4);
            short8 f;
            f[0] = (short)f2b(a0.x); f[1] = (short)f2b(a0.y);
            f[2] = (short)f2b(a0.z); f[3] = (short)f2b(a0.w);
            f[4] = (short)f2b(a1.x); f[5] = (short)f2b(a1.y);
            f[6] = (short)f2b(a1.z); f[7] = (short)f2b(a1.w);
            af[ot][ks] = f;
        }
    }

    // ---- stage X^T tile (swizzled) ----
    #pragma unroll
    for (int it = 0; it < 8; ++it) {
        const int c  = (t >> 4) + it * 16;
        const int n4 = (t & 15) * 4;
        const float4 xv = *(const float4*)(const void*)(x + base + (long)c * N_ + n0 + n4);
        const int bc = c >> 3, cl = c & 7;
        Xs[(n4 + 0) * 128 + ((bc ^ ((n4 + 0) & 15)) << 3) + cl] = (short)f2b(xv.x);
        Xs[(n4 + 1) * 128 + ((bc ^ ((n4 + 1) & 15)) << 3) + cl] = (short)f2b(xv.y);
        Xs[(n4 + 2) * 128 + ((bc ^ ((n4 + 2) & 15)) << 3) + cl] = (short)f2b(xv.z);
        Xs[(n4 + 3) * 128 + ((bc ^ ((n4 + 3) & 15)) << 3) + cl] = (short)f2b(xv.w);
    }
    __syncthreads();

    // ---- single MFMA pass ----
    f32x4 acc[2][4];
    #pragma unroll
    for (int ot = 0; ot < 2; ++ot)
        #pragma unroll
        for (int nt = 0; nt < 4; ++nt)
            acc[ot][nt] = (f32x4){0.f, 0.f, 0.f, 0.f};
    #pragma unroll
    for (int nt = 0; nt < 4; ++nt) {
        const int n = nt * 16 + l15;
        short8 bx[4];
        #pragma unroll
        for (int ks = 0; ks < 4; ++ks)
            bx[ks] = *(const short8*)(const void*)(Xs + n * 128 + (((ks * 4 + quad) ^ l15) << 3));
        #pragma unroll
        for (int ot = 0; ot < 2; ++ot)
            #pragma unroll
            for (int ks = 0; ks < 4; ++ks)
                acc[ot][nt] = __builtin_amdgcn_mfma_f32_16x16x32_bf16(af[ot][ks], bx[ks], acc[ot][nt], 0, 0, 0);
    }

    // ---- direct epilogues (no LDS, no barrier) ----
    if (p == 0) {          // q -> d_out fp32 [b][o][n], pre-scaled
        #pragma unroll
        for (int ot = 0; ot < 2; ++ot) {
            const int O0 = 32 * w + 16 * ot + quad * 4;
            const float4 bb = *(const float4*)(const void*)(bias + O0);
            #pragma unroll
            for (int r = 0; r < 4; ++r) {
                const float br = r == 0 ? bb.x : r == 1 ? bb.y : r == 2 ? bb.z : bb.w;
                #pragma unroll
                for (int nt = 0; nt < 4; ++nt)
                    q[base + (long)(O0 + r) * N_ + n0 + nt * 16 + l15] = (acc[ot][nt][r] + br) * SCALE;
            }
        }
    } else if (p == 1) {   // v -> vS bf16, swizzled 32-key windows
        #pragma unroll
        for (int ot = 0; ot < 2; ++ot) {
            const int O0 = 32 * w + 16 * ot + quad * 4;
            const float4 bb = *(const float4*)(const void*)(bias + O0);
            #pragma unroll
            for (int r = 0; r < 4; ++r) {
                const float br = r == 0 ? bb.x : r == 1 ? bb.y : r == 2 ? bb.z : bb.w;
                const int o  = O0 + r;
                const int sw = ((o >> 1) & 3) << 3;
                #pragma unroll
                for (int nt = 0; nt < 4; ++nt) {
                    const int n = nt * 16 + l15;
                    const int ns = (n & 32) | ((((n >> 3) & 3) << 3) ^ sw) | (n & 7);
                    vS[base + (long)o * N_ + n0 + ns] = f2b(acc[ot][nt][r] + br);
                }
            }
        }
    } else {               // k -> kTs bf16 [b][n][o'], direct swizzled short4
        #pragma unroll
        for (int ot = 0; ot < 2; ++ot) {
            const int O0 = 32 * w + 16 * ot + quad * 4;   // O0&7 in {0,4}: r stays in-block
            const float4 bb = *(const float4*)(const void*)(bias + O0);
            #pragma unroll
            for (int nt = 0; nt < 4; ++nt) {
                const int n = nt * 16 + l15;
                short4v s;
                s[0] = (short)f2b(acc[ot][nt][0] + bb.x);
                s[1] = (short)f2b(acc[ot][nt][1] + bb.y);
                s[2] = (short)f2b(acc[ot][nt][2] + bb.z);
                s[3] = (short)f2b(acc[ot][nt][3] + bb.w);
                *(short4v*)(void*)(kTs + base + (long)(n0 + n) * C_
                                   + (((O0 >> 3) ^ l15) << 3) + (O0 & 7)) = s;
            }
        }
    }
}

// ---------------------------------------------------------------------------
// MFMA flash attention + residual, dual key-group (R10/R11 structure).
// R13 delta: counted-vmcnt 2-barrier loop (T4) — stage(i+1) issued, then
// s_waitcnt vmcnt(4) waits only stage(i) (each wave issues exactly 4 VMEM
// ops in stage); barrier; compute(i); barrier (protects buf i&1 before
// stage(i+2) overwrites it). Prefetch stays in flight across the barrier
// instead of the __syncthreads vmcnt(0) drain. s_setprio(1) around both
// MFMA clusters (T5).
// ---------------------------------------------------------------------------
__global__ __launch_bounds__(512) void attn_mfma(
    const float* qg,                  // aliases out (q written by qkv, fp32)
    const unsigned short* __restrict__ kTs,
    const unsigned short* __restrict__ vS,
    const float* __restrict__ xg,
    float* out)
{
    __shared__ union {
        struct {
            short K[2][2][4096];      // [buf][grp][32 keys x 128 ch] swizzled
            short V[2][2][4096];      // [buf][grp][128 ch x 32 keys] swizzled
            short Pb[8][16 * 40];     // per-wave P, stride 40
        } s;
        float Ot[64 * 130];           // epilogue merge buffer
    } sm;
    __shared__ float Ls[2][4][16];    // per-group row-sums
    __shared__ float linvA[64];

    const int t    = threadIdx.x;
    const int w    = t >> 6;          // 0..7
    const int g    = w >> 2;          // key-group
    const int wq   = w & 3;           // query sub-tile
    const int lane = t & 63;
    const int l15  = lane & 15;
    const int quad = lane >> 4;

    const int b  = blockIdx.x & 7;               // XCD-pinned batch
    const int n0 = (blockIdx.x >> 3) * 64;
    const long base = (long)b * C_ * N_;

    // ---- Q A-frags (q pre-scaled by 1/sqrt(C)) ----
    const int query = n0 + 16 * wq + l15;
    short8 qf[4];
    #pragma unroll
    for (int ks = 0; ks < 4; ++ks) {
        short8 f;
        #pragma unroll
        for (int j = 0; j < 8; ++j) {
            const int c = ks * 32 + quad * 8 + j;
            f[j] = (short)f2b(qg[base + (long)c * N_ + query]);
        }
        qf[ks] = f;
    }

    f32x4 acc[8];
    #pragma unroll
    for (int ct = 0; ct < 8; ++ct) acc[ct] = (f32x4){0.f, 0.f, 0.f, 0.f};
    f32x4 accS = (f32x4){0.f, 0.f, 0.f, 0.f};
    short8 ones;
    #pragma unroll
    for (int j = 0; j < 8; ++j) ones[j] = (short)0x3F80;   // bf16 1.0

    auto stage = [&](int buf, int pair) {        // exactly 4 VMEM ops / lane
        const int mt = pair * 2 + g;
        const char* gK = (const char*)(kTs + base + (long)mt * 32 * C_);
        char* lK = (char*)sm.s.K[buf][g];
        char* lV = (char*)sm.s.V[buf][g];
        #pragma unroll
        for (int jj = 0; jj < 2; ++jj) {
            const int d = wq * 2048 + jj * 1024;
            gld_lds16(gK + d + lane * 16, lK + d);
            const int dv = d + lane * 16;
            const int c  = dv >> 6;
            gld_lds16((const char*)(vS + base + (long)c * N_ + mt * 32) + (dv & 63), lV + d);
        }
    };

    auto compute = [&](int buf) {
        const short* Kb = sm.s.K[buf][g];
        const short* Vb = sm.s.V[buf][g];
        f32x4 sc[2];
        sc[0] = (f32x4){0.f, 0.f, 0.f, 0.f};
        sc[1] = (f32x4){0.f, 0.f, 0.f, 0.f};
        __builtin_amdgcn_s_setprio(1);
        #pragma unroll
        for (int kt = 0; kt < 2; ++kt) {
            const int row = (kt * 16 + l15) * 128;
            #pragma unroll
            for (int ks = 0; ks < 4; ++ks) {
                const short8 kf = *(const short8*)(const void*)(Kb + row + (((ks * 4 + quad) ^ l15) << 3));
                sc[kt] = __builtin_amdgcn_mfma_f32_16x16x32_bf16(qf[ks], kf, sc[kt], 0, 0, 0);
            }
        }
        __builtin_amdgcn_s_setprio(0);
        short* Pw = sm.s.Pb[w];
        #pragma unroll
        for (int kt = 0; kt < 2; ++kt)
            #pragma unroll
            for (int r = 0; r < 4; ++r)
                Pw[(quad * 4 + r) * 40 + kt * 16 + l15] = (short)f2b(__expf(sc[kt][r]));
        const short8 pf = *(const short8*)(const void*)(Pw + l15 * 40 + quad * 8);
        __builtin_amdgcn_s_setprio(1);
        accS = __builtin_amdgcn_mfma_f32_16x16x32_bf16(pf, ones, accS, 0, 0, 0);
        #pragma unroll
        for (int ct = 0; ct < 8; ++ct) {
            const short8 vf = *(const short8*)(const void*)(Vb + (ct * 16 + l15) * 32 + ((quad ^ ((l15 >> 1) & 3)) << 3));
            acc[ct] = __builtin_amdgcn_mfma_f32_16x16x32_bf16(pf, vf, acc[ct], 0, 0, 0);
        }
        __builtin_amdgcn_s_setprio(0);
    };

    stage(0, 0);
    for (int i = 0; i < 64; ++i) {
        if (i < 63) {
            stage((i + 1) & 1, i + 1);
            asm volatile("s_waitcnt vmcnt(4)" ::: "memory");   // stage(i) done (own 4)
        } else {
            asm volatile("s_waitcnt vmcnt(0)" ::: "memory");
        }
        __builtin_amdgcn_s_barrier();      // everyone's stage(i) visible
        compute(i & 1);
        __builtin_amdgcn_s_barrier();      // buf i&1 reads done before next stage
    }

    // ---- merge epilogue: Ot = O_g0 + O_g1; l via Ls; normalize + residual ----
    if (l15 == 0) {
        #pragma unroll
        for (int r = 0; r < 4; ++r) Ls[g][wq][quad * 4 + r] = accS[r];
    }
    if (g == 0) {
        #pragma unroll
        for (int ct = 0; ct < 8; ++ct)
            #pragma unroll
            for (int r = 0; r < 4; ++r)
                sm.Ot[(16 * wq + quad * 4 + r) * 130 + ct * 16 + l15] = acc[ct][r];
    }
    __syncthreads();
    if (g == 1) {
        #pragma unroll
        for (int ct = 0; ct < 8; ++ct)
            #pragma unroll
            for (int r = 0; r < 4; ++r)
                sm.Ot[(16 * wq + quad * 4 + r) * 130 + ct * 16 + l15] += acc[ct][r];
    } else if (l15 == 0) {
        #pragma unroll
        for (int r = 0; r < 4; ++r) {
            const int row = 16 * wq + quad * 4 + r;
            linvA[row] = 1.0f / fmaxf(Ls[0][wq][quad * 4 + r] + Ls[1][wq][quad * 4 + r], 1e-20f);
        }
    }
    __syncthreads();

    const int c  = t >> 2;
    const int nh = (t & 3) * 16;
    const long gb = base + (long)c * N_ + n0 + nh;
    #pragma unroll
    for (int i = 0; i < 16; i += 4) {
        const float4 xs = *(const float4*)(const void*)(xg + gb + i);
        float4 rv;
        rv.x = sm.Ot[(nh + i + 0) * 130 + c] * linvA[nh + i + 0] + xs.x;
        rv.y = sm.Ot[(nh + i + 1) * 130 + c] * linvA[nh + i + 1] + xs.y;
        rv.z = sm.Ot[(nh + i + 2) * 130 + c] * linvA[nh + i + 2] + xs.z;
        rv.w = sm.Ot[(nh + i + 3) * 130 + c] * linvA[nh + i + 3] + xs.w;
        *(float4*)(void*)(out + gb + i) = rv;
    }
}

// ---------------------------------------------------------------------------
extern "C" void kernel_launch(void* const* d_in, const int* in_sizes, int n_in,
                              void* d_out, int out_size, void* d_ws, size_t ws_size,
                              hipStream_t stream) {
    const float* x  = (const float*)d_in[0];
    const float* Wq = (const float*)d_in[1];
    const float* bq = (const float*)d_in[2];
    const float* Wk = (const float*)d_in[3];
    const float* bk = (const float*)d_in[4];
    const float* Wv = (const float*)d_in[5];
    const float* bv = (const float*)d_in[6];
    float* out = (float*)d_out;

    const long BCN = (long)B_ * C_ * N_;                  // 4,194,304
    unsigned short* kTs = (unsigned short*)d_ws;          // [b][n][o'] bf16 swizzled
    unsigned short* vS  = kTs + BCN;                      // [b][o][n'] bf16 swizzled

    // q lives in d_out [b][c][n] fp32 (pre-scaled): each attn block reads only
    // its own query columns and overwrites exactly those columns at the end.
    qkv_mfma<<<1536, 256, 0, stream>>>(x, Wq, bq, Wk, bk, Wv, bv, out, kTs, vS);
    attn_mfma<<<B_ * (N_ / 64), 512, 0, stream>>>(out, kTs, vS, x, out);
}

// Round 2
// 198.201 us; speedup vs baseline: 1.0078x; 1.0078x over previous
//
#include <hip/hip_runtime.h>

#define B_ 8
#define C_ 128
#define N_ 4096
// 1/sqrt(128) * log2(e): q pre-scaled so attn uses exp2 (native v_exp_f32)
#define SCALE_L2E 0.1275174462578437f

typedef __attribute__((ext_vector_type(8))) short short8;   // 8 bf16
typedef __attribute__((ext_vector_type(4))) short short4v;  // 4 bf16
typedef __attribute__((ext_vector_type(4))) float f32x4;    // MFMA C/D

__device__ inline float b2f(unsigned short u) {
    union { unsigned int i; float f; } v; v.i = ((unsigned int)u) << 16; return v.f;
}
__device__ inline unsigned short f2b(float f) {            // RNE bf16 round
    unsigned int x = __float_as_uint(f);
    return (unsigned short)((x + 0x7FFFu + ((x >> 16) & 1u)) >> 16);
}

// async global->LDS, 16B per lane (m97 staging path).
__device__ inline void gld_lds16(const void* g, void* l) {
    __builtin_amdgcn_global_load_lds(
        (const __attribute__((address_space(1))) unsigned int*)g,
        (__attribute__((address_space(3))) unsigned int*)l, 16, 0, 0);
}

// ---------------------------------------------------------------------------
// MFMA QKV projection — R0 monolithic structure (76.6 us proven; R13's
// pass-split regressed to ~84 by losing W-prefetch overlap + 3x X staging).
// Only delta vs R0: q pre-scale includes log2(e) (attn uses exp2).
//  - pass order q -> v -> k, W A-frags of the NEXT pass prefetched before the
//    current pass's 32 MFMAs.
//  - q and v store DIRECTLY from C/D regs; only k keeps the Obuf epilogue.
// kTs bf16 [b][n][o'] o-blocks ^ (n&15). vS bf16 [b][o][n'] 32-key windows,
// block' ^= (o>>1)&3. XCD map b = bid&7.
// mfma_f32_16x16x32_bf16: A[m=l15][k=quad*8+j]; B[k][n=l15];
// C/D row=quad*4+r, col=l15 (R6-R11 proven).
// ---------------------------------------------------------------------------
__global__ __launch_bounds__(256) void qkv_mfma(
    const float* __restrict__ x,
    const float* __restrict__ Wq, const float* __restrict__ bq,
    const float* __restrict__ Wk, const float* __restrict__ bk,
    const float* __restrict__ Wv, const float* __restrict__ bv,
    float* __restrict__ q, unsigned short* __restrict__ kTs,
    unsigned short* __restrict__ vS)
{
    __shared__ __align__(16) short Xs[64 * 128];    // 16 KB bf16 X^T, swizzled
    __shared__ __align__(16) float Obuf[64 * 132];  // 33.8 KB k-epilogue

    const int t    = threadIdx.x;
    const int w    = t >> 6;
    const int lane = t & 63;
    const int l15  = lane & 15;
    const int quad = lane >> 4;

    const int b  = blockIdx.x & 7;               // XCD-pinned batch
    const int n0 = (blockIdx.x >> 3) * 64;
    const long base = (long)b * C_ * N_;

    auto load_af = [&](const float* __restrict__ W, short8 (&af)[2][4]) {
        #pragma unroll
        for (int ot = 0; ot < 2; ++ot) {
            const int o = 32 * w + 16 * ot + l15;
            #pragma unroll
            for (int ks = 0; ks < 4; ++ks) {
                const float4 a0 = *(const float4*)(const void*)(W + o * C_ + ks * 32 + quad * 8);
                const float4 a1 = *(const float4*)(const void*)(W + o * C_ + ks * 32 + quad * 8 + 4);
                short8 f;
                f[0] = (short)f2b(a0.x); f[1] = (short)f2b(a0.y);
                f[2] = (short)f2b(a0.z); f[3] = (short)f2b(a0.w);
                f[4] = (short)f2b(a1.x); f[5] = (short)f2b(a1.y);
                f[6] = (short)f2b(a1.z); f[7] = (short)f2b(a1.w);
                af[ot][ks] = f;
            }
        }
    };

    auto mfma_pass = [&](const short8 (&af)[2][4], f32x4 (&acc)[2][4]) {
        #pragma unroll
        for (int ot = 0; ot < 2; ++ot)
            #pragma unroll
            for (int nt = 0; nt < 4; ++nt)
                acc[ot][nt] = (f32x4){0.f, 0.f, 0.f, 0.f};
        #pragma unroll
        for (int nt = 0; nt < 4; ++nt) {
            const int n = nt * 16 + l15;
            short8 bx[4];
            #pragma unroll
            for (int ks = 0; ks < 4; ++ks)
                bx[ks] = *(const short8*)(const void*)(Xs + n * 128 + (((ks * 4 + quad) ^ l15) << 3));
            #pragma unroll
            for (int ot = 0; ot < 2; ++ot)
                #pragma unroll
                for (int ks = 0; ks < 4; ++ks)
                    acc[ot][nt] = __builtin_amdgcn_mfma_f32_16x16x32_bf16(af[ot][ks], bx[ks], acc[ot][nt], 0, 0, 0);
        }
    };

    // ---- W(q) A-frags first, then stage X^T tile ----
    short8 afA[2][4], afB[2][4];
    load_af(Wq, afA);

    #pragma unroll
    for (int it = 0; it < 8; ++it) {
        const int c  = (t >> 4) + it * 16;
        const int n4 = (t & 15) * 4;
        const float4 xv = *(const float4*)(const void*)(x + base + (long)c * N_ + n0 + n4);
        const int bc = c >> 3, cl = c & 7;
        Xs[(n4 + 0) * 128 + ((bc ^ ((n4 + 0) & 15)) << 3) + cl] = (short)f2b(xv.x);
        Xs[(n4 + 1) * 128 + ((bc ^ ((n4 + 1) & 15)) << 3) + cl] = (short)f2b(xv.y);
        Xs[(n4 + 2) * 128 + ((bc ^ ((n4 + 2) & 15)) << 3) + cl] = (short)f2b(xv.z);
        Xs[(n4 + 3) * 128 + ((bc ^ ((n4 + 3) & 15)) << 3) + cl] = (short)f2b(xv.w);
    }
    __syncthreads();

    { // ======== pass 1: q -> d_out fp32 [b][o][n], pre-scaled (x log2e) ========
        load_af(Wv, afB);                          // prefetch v weights
        f32x4 acc[2][4];
        mfma_pass(afA, acc);
        #pragma unroll
        for (int ot = 0; ot < 2; ++ot)
            #pragma unroll
            for (int r = 0; r < 4; ++r) {
                const int o = 32 * w + 16 * ot + quad * 4 + r;
                const float bb = bq[o];
                #pragma unroll
                for (int nt = 0; nt < 4; ++nt)
                    q[base + (long)o * N_ + n0 + nt * 16 + l15] = (acc[ot][nt][r] + bb) * SCALE_L2E;
            }
    }

    { // ======== pass 2: v -> vS bf16, direct swizzled store ========
        load_af(Wk, afA);                          // prefetch k weights
        f32x4 acc[2][4];
        mfma_pass(afB, acc);
        #pragma unroll
        for (int ot = 0; ot < 2; ++ot)
            #pragma unroll
            for (int r = 0; r < 4; ++r) {
                const int o = 32 * w + 16 * ot + quad * 4 + r;
                const float bb = bv[o];
                const int sw = ((o >> 1) & 3) << 3;
                #pragma unroll
                for (int nt = 0; nt < 4; ++nt) {
                    const int n = nt * 16 + l15;
                    const int ns = (n & 32) | ((((n >> 3) & 3) << 3) ^ sw) | (n & 7);
                    vS[base + (long)o * N_ + n0 + ns] = f2b(acc[ot][nt][r] + bb);
                }
            }
    }

    { // ======== pass 3: k -> kTs bf16 [b][n][o'] via Obuf (stride 132) ========
        f32x4 acc[2][4];
        mfma_pass(afA, acc);
        #pragma unroll
        for (int ot = 0; ot < 2; ++ot)
            #pragma unroll
            for (int r = 0; r < 4; ++r) {
                const int o = 32 * w + 16 * ot + quad * 4 + r;
                const float bb = bk[o];
                #pragma unroll
                for (int nt = 0; nt < 4; ++nt) {
                    const int n = nt * 16 + l15;
                    Obuf[n * 132 + (((o >> 3) ^ l15) << 3) + (o & 7)] = acc[ot][nt][r] + bb;
                }
            }
        __syncthreads();
        const int n = t >> 2, oh = (t & 3) * 32;
        #pragma unroll
        for (int i = 0; i < 32; i += 4) {
            const float4 kv = *(const float4*)(const void*)(Obuf + n * 132 + oh + i);
            short4v s;
            s[0] = (short)f2b(kv.x); s[1] = (short)f2b(kv.y);
            s[2] = (short)f2b(kv.z); s[3] = (short)f2b(kv.w);
            *(short4v*)(void*)(kTs + base + (long)(n0 + n) * C_ + oh + i) = s;
        }
    }
}

// ---------------------------------------------------------------------------
// MFMA flash attention + residual. R14 restructure: attn was LDS-BW-bound
// (16 waves/CU x 17KB ds_read per iter ~ 288KB/iter-slot ~ 75% of wall at
// ~90B/cyc; MfmaUtil 26% matches MFMA's 31% share). Fix: 2x queries per
// wave so K/V frag reads amortize — block-iter LDS reads 136KB -> 80KB.
// Wave roles (w = g*4 + wq*2 + h):
//   QK phase: wave (g,wq,kh=h) computes P[32q(wq)][16k(kh)] of group g's
//             32-key tile; K-frag reads 4KB/wave (rows kh*16+l15, same
//             swizzle as before).
//   PV phase: wave (g,wq,h) reads FULL P[32q][32k] (shared in LDS; one
//             extra barrier) and computes ch-half h: V reads 4KB/wave.
// All MFMAs stay 16x16x32; acc = 32q x 64c = 32 VGPR. kTs/vS/staging and
// the R1-proven counted-vmcnt loop are unchanged. exp2f (q pre-scaled by
// log2e). setprio around MFMA clusters (T5).
// ---------------------------------------------------------------------------
__global__ __launch_bounds__(512, 4) void attn_mfma(
    const float* qg,                  // aliases out (q written by qkv, fp32)
    const unsigned short* __restrict__ kTs,
    const unsigned short* __restrict__ vS,
    const float* __restrict__ xg,
    float* out)
{
    __shared__ union {
        struct {
            short K[2][2][4096];      // [buf][grp][32 keys x 128 ch] swizzled
            short V[2][2][4096];      // [buf][grp][128 ch x 32 keys] swizzled
            short Pb[2][2][32 * 40];  // [grp][wq] 32q x 32k, stride 40
        } s;
        float Ot[64 * 130];           // epilogue merge buffer
    } sm;
    __shared__ float Ls[2][2][32];    // [g][wq][row32] row-sums
    __shared__ float linvA[64];

    const int t    = threadIdx.x;
    const int w    = t >> 6;          // 0..7
    const int g    = w >> 2;          // key-group (2048-key half)
    const int wq   = (w >> 1) & 1;    // 32-query subtile
    const int h    = w & 1;           // QK: key-half kh; PV: channel-half
    const int sub  = w & 3;           // staging sub-tile (as before)
    const int lane = t & 63;
    const int l15  = lane & 15;
    const int quad = lane >> 4;

    const int b  = blockIdx.x & 7;               // XCD-pinned batch
    const int n0 = (blockIdx.x >> 3) * 64;
    const long base = (long)b * C_ * N_;

    // ---- Q A-frags: 32 queries per wave (2 x 16q subtiles) ----
    const int query0 = n0 + 32 * wq;
    short8 qf[2][4];
    #pragma unroll
    for (int qh = 0; qh < 2; ++qh)
        #pragma unroll
        for (int ks = 0; ks < 4; ++ks) {
            short8 f;
            #pragma unroll
            for (int j = 0; j < 8; ++j) {
                const int c = ks * 32 + quad * 8 + j;
                f[j] = (short)f2b(qg[base + (long)c * N_ + query0 + qh * 16 + l15]);
            }
            qf[qh][ks] = f;
        }

    f32x4 acc[2][4];                  // [qh][ct]: 32q x 64c (half-channels h)
    #pragma unroll
    for (int qh = 0; qh < 2; ++qh)
        #pragma unroll
        for (int ct = 0; ct < 4; ++ct) acc[qh][ct] = (f32x4){0.f, 0.f, 0.f, 0.f};
    f32x4 accS[2];
    accS[0] = (f32x4){0.f, 0.f, 0.f, 0.f};
    accS[1] = (f32x4){0.f, 0.f, 0.f, 0.f};
    short8 ones;
    #pragma unroll
    for (int j = 0; j < 8; ++j) ones[j] = (short)0x3F80;   // bf16 1.0

    auto stage = [&](int buf, int pair) {        // exactly 4 VMEM ops / lane
        const int mt = pair * 2 + g;
        const char* gK = (const char*)(kTs + base + (long)mt * 32 * C_);
        char* lK = (char*)sm.s.K[buf][g];
        char* lV = (char*)sm.s.V[buf][g];
        #pragma unroll
        for (int jj = 0; jj < 2; ++jj) {
            const int d = sub * 2048 + jj * 1024;
            gld_lds16(gK + d + lane * 16, lK + d);
            const int dv = d + lane * 16;
            const int c  = dv >> 6;
            gld_lds16((const char*)(vS + base + (long)c * N_ + mt * 32) + (dv & 63), lV + d);
        }
    };

    stage(0, 0);
    for (int i = 0; i < 64; ++i) {
        if (i < 63) {
            stage((i + 1) & 1, i + 1);
            asm volatile("s_waitcnt vmcnt(4)" ::: "memory");   // own stage(i) done
        } else {
            asm volatile("s_waitcnt vmcnt(0)" ::: "memory");
        }
        __builtin_amdgcn_s_barrier();          // K/V(i) visible to all waves

        const int buf = i & 1;
        const short* Kb = sm.s.K[buf][g];
        const short* Vb = sm.s.V[buf][g];

        // ---- QK phase: P[32q][16k] for key-half h ----
        short8 kf[4];
        #pragma unroll
        for (int ks = 0; ks < 4; ++ks)
            kf[ks] = *(const short8*)(const void*)(Kb + (h * 16 + l15) * 128 + (((ks * 4 + quad) ^ l15) << 3));
        f32x4 sc[2];
        sc[0] = (f32x4){0.f, 0.f, 0.f, 0.f};
        sc[1] = (f32x4){0.f, 0.f, 0.f, 0.f};
        __builtin_amdgcn_s_setprio(1);
        #pragma unroll
        for (int qh = 0; qh < 2; ++qh)
            #pragma unroll
            for (int ks = 0; ks < 4; ++ks)
                sc[qh] = __builtin_amdgcn_mfma_f32_16x16x32_bf16(qf[qh][ks], kf[ks], sc[qh], 0, 0, 0);
        __builtin_amdgcn_s_setprio(0);

        short* Pw = sm.s.Pb[g][wq];
        #pragma unroll
        for (int qh = 0; qh < 2; ++qh)
            #pragma unroll
            for (int r = 0; r < 4; ++r)
                Pw[(qh * 16 + quad * 4 + r) * 40 + h * 16 + l15] = (short)f2b(exp2f(sc[qh][r]));

        asm volatile("s_waitcnt lgkmcnt(0)" ::: "memory");
        __builtin_amdgcn_s_barrier();          // full P tile visible
        __builtin_amdgcn_sched_barrier(0);

        // ---- PV phase: channel-half h, full 32-key P ----
        const short8 pf0 = *(const short8*)(const void*)(Pw + (l15) * 40 + quad * 8);
        const short8 pf1 = *(const short8*)(const void*)(Pw + (16 + l15) * 40 + quad * 8);
        __builtin_amdgcn_s_setprio(1);
        if (h == 0) {                          // row-sums once per (g,wq)
            accS[0] = __builtin_amdgcn_mfma_f32_16x16x32_bf16(pf0, ones, accS[0], 0, 0, 0);
            accS[1] = __builtin_amdgcn_mfma_f32_16x16x32_bf16(pf1, ones, accS[1], 0, 0, 0);
        }
        #pragma unroll
        for (int ct = 0; ct < 4; ++ct) {
            const int ch = h * 64 + ct * 16 + l15;
            const short8 vf = *(const short8*)(const void*)(Vb + ch * 32 + ((quad ^ ((l15 >> 1) & 3)) << 3));
            acc[0][ct] = __builtin_amdgcn_mfma_f32_16x16x32_bf16(pf0, vf, acc[0][ct], 0, 0, 0);
            acc[1][ct] = __builtin_amdgcn_mfma_f32_16x16x32_bf16(pf1, vf, acc[1][ct], 0, 0, 0);
        }
        __builtin_amdgcn_s_setprio(0);
        __builtin_amdgcn_s_barrier();          // V/P reads done before overwrite
    }

    // ---- merge epilogue ----
    if (h == 0 && l15 == 0) {
        #pragma unroll
        for (int qh = 0; qh < 2; ++qh)
            #pragma unroll
            for (int r = 0; r < 4; ++r)
                Ls[g][wq][qh * 16 + quad * 4 + r] = accS[qh][r];
    }
    if (g == 0) {
        #pragma unroll
        for (int qh = 0; qh < 2; ++qh)
            #pragma unroll
            for (int ct = 0; ct < 4; ++ct)
                #pragma unroll
                for (int r = 0; r < 4; ++r)
                    sm.Ot[(32 * wq + qh * 16 + quad * 4 + r) * 130 + h * 64 + ct * 16 + l15] = acc[qh][ct][r];
    }
    __syncthreads();
    if (g == 1) {
        #pragma unroll
        for (int qh = 0; qh < 2; ++qh)
            #pragma unroll
            for (int ct = 0; ct < 4; ++ct)
                #pragma unroll
                for (int r = 0; r < 4; ++r)
                    sm.Ot[(32 * wq + qh * 16 + quad * 4 + r) * 130 + h * 64 + ct * 16 + l15] += acc[qh][ct][r];
    } else if (h == 0 && l15 == 0) {
        #pragma unroll
        for (int qh = 0; qh < 2; ++qh)
            #pragma unroll
            for (int r = 0; r < 4; ++r) {
                const int r32 = qh * 16 + quad * 4 + r;
                linvA[32 * wq + r32] = 1.0f / fmaxf(Ls[0][wq][r32] + Ls[1][wq][r32], 1e-20f);
            }
    }
    __syncthreads();

    const int c  = t >> 2;
    const int nh = (t & 3) * 16;
    const long gb = base + (long)c * N_ + n0 + nh;
    #pragma unroll
    for (int i = 0; i < 16; i += 4) {
        const float4 xs = *(const float4*)(const void*)(xg + gb + i);
        float4 rv;
        rv.x = sm.Ot[(nh + i + 0) * 130 + c] * linvA[nh + i + 0] + xs.x;
        rv.y = sm.Ot[(nh + i + 1) * 130 + c] * linvA[nh + i + 1] + xs.y;
        rv.z = sm.Ot[(nh + i + 2) * 130 + c] * linvA[nh + i + 2] + xs.z;
        rv.w = sm.Ot[(nh + i + 3) * 130 + c] * linvA[nh + i + 3] + xs.w;
        *(float4*)(void*)(out + gb + i) = rv;
    }
}

// ---------------------------------------------------------------------------
extern "C" void kernel_launch(void* const* d_in, const int* in_sizes, int n_in,
                              void* d_out, int out_size, void* d_ws, size_t ws_size,
                              hipStream_t stream) {
    const float* x  = (const float*)d_in[0];
    const float* Wq = (const float*)d_in[1];
    const float* bq = (const float*)d_in[2];
    const float* Wk = (const float*)d_in[3];
    const float* bk = (const float*)d_in[4];
    const float* Wv = (const float*)d_in[5];
    const float* bv = (const float*)d_in[6];
    float* out = (float*)d_out;

    const long BCN = (long)B_ * C_ * N_;                  // 4,194,304
    unsigned short* kTs = (unsigned short*)d_ws;          // [b][n][o'] bf16 swizzled
    unsigned short* vS  = kTs + BCN;                      // [b][o][n'] bf16 swizzled

    // q lives in d_out [b][c][n] fp32 (pre-scaled by log2e/sqrt(C)): each attn
    // block reads only its own query columns and overwrites exactly those.
    qkv_mfma<<<512, 256, 0, stream>>>(x, Wq, bq, Wk, bk, Wv, bv, out, kTs, vS);
    attn_mfma<<<B_ * (N_ / 64), 512, 0, stream>>>(out, kTs, vS, x, out);
}

// Round 3
// 188.836 us; speedup vs baseline: 1.0578x; 1.0496x over previous
//
#include <hip/hip_runtime.h>

#define B_ 8
#define C_ 128
#define N_ 4096
#define SCALE 0.08838834764831845f   // 1/sqrt(128)

typedef __attribute__((ext_vector_type(8))) short short8;   // 8 bf16
typedef __attribute__((ext_vector_type(4))) short short4v;  // 4 bf16
typedef __attribute__((ext_vector_type(4))) float f32x4;    // MFMA C/D

__device__ inline float b2f(unsigned short u) {
    union { unsigned int i; float f; } v; v.i = ((unsigned int)u) << 16; return v.f;
}
__device__ inline unsigned short f2b(float f) {            // RNE bf16 round
    unsigned int x = __float_as_uint(f);
    return (unsigned short)((x + 0x7FFFu + ((x >> 16) & 1u)) >> 16);
}

// async global->LDS, 16B per lane (m97 staging path).
__device__ inline void gld_lds16(const void* g, void* l) {
    __builtin_amdgcn_global_load_lds(
        (const __attribute__((address_space(1))) unsigned int*)g,
        (__attribute__((address_space(3))) unsigned int*)l, 16, 0, 0);
}

// ---------------------------------------------------------------------------
// MFMA QKV projection, R15: monolithic q->v->k chain (R0-proven prefetch
// overlap) but O-HALVED: grid 1024 = 8b x 2 oh x 64 n-tiles, each block does
// 64 output channels -> 4 blocks/CU (was 2; kernel is latency-bound, 42 TF).
// Obuf eliminated via R1-proven direct swizzled short4 k-store (O0&7 in
// {0,4} so r=0..3 never crosses an 8-block). LDS = 16KB Xs only, 1 barrier.
// kTs bf16 [b][n][o'] o-blocks ^ (n&15). vS bf16 [b][o][n'] 32-key windows,
// block' ^= (o>>1)&3. q fp32 pre-scaled by 1/sqrt(C) -> d_out.
// mfma_f32_16x16x32_bf16: A[m=l15][k=quad*8+j]; B[k][n=l15];
// C/D row=quad*4+r, col=l15 (R6-R11 proven).
// ---------------------------------------------------------------------------
__global__ __launch_bounds__(256) void qkv_mfma(
    const float* __restrict__ x,
    const float* __restrict__ Wq, const float* __restrict__ bq,
    const float* __restrict__ Wk, const float* __restrict__ bk,
    const float* __restrict__ Wv, const float* __restrict__ bv,
    float* __restrict__ q, unsigned short* __restrict__ kTs,
    unsigned short* __restrict__ vS)
{
    __shared__ __align__(16) short Xs[64 * 128];    // 16 KB bf16 X^T, swizzled

    const int t    = threadIdx.x;
    const int w    = t >> 6;          // 0..3
    const int lane = t & 63;
    const int l15  = lane & 15;
    const int quad = lane >> 4;

    const int b    = blockIdx.x & 7;             // XCD-pinned batch
    const int rest = blockIdx.x >> 3;            // 0..127
    const int oh   = rest & 1;                   // output-channel half
    const int n0   = (rest >> 1) * 64;
    const long base = (long)b * C_ * N_;

    auto load_af = [&](const float* __restrict__ W, short8 (&af)[4]) {
        const int o = oh * 64 + 16 * w + l15;
        #pragma unroll
        for (int ks = 0; ks < 4; ++ks) {
            const float4 a0 = *(const float4*)(const void*)(W + o * C_ + ks * 32 + quad * 8);
            const float4 a1 = *(const float4*)(const void*)(W + o * C_ + ks * 32 + quad * 8 + 4);
            short8 f;
            f[0] = (short)f2b(a0.x); f[1] = (short)f2b(a0.y);
            f[2] = (short)f2b(a0.z); f[3] = (short)f2b(a0.w);
            f[4] = (short)f2b(a1.x); f[5] = (short)f2b(a1.y);
            f[6] = (short)f2b(a1.z); f[7] = (short)f2b(a1.w);
            af[ks] = f;
        }
    };

    auto mfma_pass = [&](const short8 (&af)[4], f32x4 (&acc)[4]) {
        #pragma unroll
        for (int nt = 0; nt < 4; ++nt) acc[nt] = (f32x4){0.f, 0.f, 0.f, 0.f};
        #pragma unroll
        for (int nt = 0; nt < 4; ++nt) {
            const int n = nt * 16 + l15;
            #pragma unroll
            for (int ks = 0; ks < 4; ++ks) {
                const short8 bx = *(const short8*)(const void*)(Xs + n * 128 + (((ks * 4 + quad) ^ l15) << 3));
                acc[nt] = __builtin_amdgcn_mfma_f32_16x16x32_bf16(af[ks], bx, acc[nt], 0, 0, 0);
            }
        }
    };

    // ---- W(q) A-frags first, then stage X^T tile (full 128 c) ----
    short8 afA[4], afB[4];
    load_af(Wq, afA);

    #pragma unroll
    for (int it = 0; it < 8; ++it) {
        const int c  = (t >> 4) + it * 16;
        const int n4 = (t & 15) * 4;
        const float4 xv = *(const float4*)(const void*)(x + base + (long)c * N_ + n0 + n4);
        const int bc = c >> 3, cl = c & 7;
        Xs[(n4 + 0) * 128 + ((bc ^ ((n4 + 0) & 15)) << 3) + cl] = (short)f2b(xv.x);
        Xs[(n4 + 1) * 128 + ((bc ^ ((n4 + 1) & 15)) << 3) + cl] = (short)f2b(xv.y);
        Xs[(n4 + 2) * 128 + ((bc ^ ((n4 + 2) & 15)) << 3) + cl] = (short)f2b(xv.z);
        Xs[(n4 + 3) * 128 + ((bc ^ ((n4 + 3) & 15)) << 3) + cl] = (short)f2b(xv.w);
    }
    __syncthreads();

    const int O0 = oh * 64 + 16 * w + quad * 4;

    { // ======== pass 1: q -> d_out fp32 [b][o][n], pre-scaled ========
        load_af(Wv, afB);                          // prefetch v weights
        f32x4 acc[4];
        mfma_pass(afA, acc);
        #pragma unroll
        for (int r = 0; r < 4; ++r) {
            const int o = O0 + r;
            const float bb = bq[o];
            #pragma unroll
            for (int nt = 0; nt < 4; ++nt)
                q[base + (long)o * N_ + n0 + nt * 16 + l15] = (acc[nt][r] + bb) * SCALE;
        }
    }

    { // ======== pass 2: v -> vS bf16, direct swizzled store ========
        load_af(Wk, afA);                          // prefetch k weights
        f32x4 acc[4];
        mfma_pass(afB, acc);
        #pragma unroll
        for (int r = 0; r < 4; ++r) {
            const int o = O0 + r;
            const float bb = bv[o];
            const int sw = ((o >> 1) & 3) << 3;
            #pragma unroll
            for (int nt = 0; nt < 4; ++nt) {
                const int n = nt * 16 + l15;
                const int ns = (n & 32) | ((((n >> 3) & 3) << 3) ^ sw) | (n & 7);
                vS[base + (long)o * N_ + n0 + ns] = f2b(acc[nt][r] + bb);
            }
        }
    }

    { // ======== pass 3: k -> kTs bf16 [b][n][o'], direct swizzled short4 ====
        f32x4 acc[4];
        mfma_pass(afA, acc);
        const float4 bb = *(const float4*)(const void*)(bk + O0);
        #pragma unroll
        for (int nt = 0; nt < 4; ++nt) {
            const int n = nt * 16 + l15;
            short4v s;
            s[0] = (short)f2b(acc[nt][0] + bb.x);
            s[1] = (short)f2b(acc[nt][1] + bb.y);
            s[2] = (short)f2b(acc[nt][2] + bb.z);
            s[3] = (short)f2b(acc[nt][3] + bb.w);
            *(short4v*)(void*)(kTs + base + (long)(n0 + n) * C_
                               + (((O0 >> 3) ^ l15) << 3) + (O0 & 7)) = s;
        }
    }
}

// ---------------------------------------------------------------------------
// MFMA flash attention + residual, R15. LDS-pipe cost model (R1: 17 b128 +
// 8 b16 per wave/iter ~ 250cy x16 waves ~ 4000cy ~ measured 4450cy wall)
// says ds-instruction cost + lockstep phases dominate. Fixes:
//  - K frags load GLOBAL->REG (kTs swizzle works per-lane since key&15=l15);
//    single reg buffer, prefetched right after QK(i) consumes it (~1 iter in
//    flight, L2-resident). K LDS staging + reads GONE.
//  - ONE barrier per iter: QK is register-only, so {V(i) ready, P(i) ready}
//    are both gated by a single vmcnt(4)+lgkmcnt(0)+s_barrier before PV.
//    P double-buffered by iter parity (Pw(i+1) can't race slow pf(i) reads);
//    V(i+1) stage issued right after B(i) -> every PV(i-1) read of that
//    buffer completed before any wave passed B(i).
//  - counted vmcnt(4): kf(i+1) stays in flight across the barrier.
//  - __expf (2 inst) — R2's exp2f was a ~25-inst libcall (VALUBusy 32->46).
// Per-wave LDS/iter: 8 ds_write_b16 + 2+4 ds_read_b128 ~ 118cy (was 250).
// ---------------------------------------------------------------------------
__global__ __launch_bounds__(512, 4) void attn_mfma(
    const float* qg,                  // aliases out (q written by qkv, fp32)
    const unsigned short* __restrict__ kTs,
    const unsigned short* __restrict__ vS,
    const float* __restrict__ xg,
    float* out)
{
    __shared__ union {
        struct {
            short V[2][2][4096];         // [buf][grp][128 ch x 32 keys] swizzled
            short Pb[2][2][2][32 * 40];  // [iter-parity][grp][wq] 32q x 32k
        } s;
        float Ot[64 * 130];              // epilogue merge buffer
    } sm;
    __shared__ float Ls[2][2][32];       // [g][wq][row32] row-sums
    __shared__ float linvA[64];

    const int t    = threadIdx.x;
    const int w    = t >> 6;          // 0..7
    const int g    = w >> 2;          // key-group (2048-key half)
    const int wq   = (w >> 1) & 1;    // 32-query subtile
    const int h    = w & 1;           // QK: key-half; PV: channel-half
    const int sub  = w & 3;           // staging sub-tile
    const int lane = t & 63;
    const int l15  = lane & 15;
    const int quad = lane >> 4;

    const int b  = blockIdx.x & 7;               // XCD-pinned batch
    const int n0 = (blockIdx.x >> 3) * 64;
    const long base = (long)b * C_ * N_;

    // ---- Q A-frags: 32 queries per wave (2 x 16q subtiles) ----
    const int query0 = n0 + 32 * wq;
    short8 qf[2][4];
    #pragma unroll
    for (int qh = 0; qh < 2; ++qh)
        #pragma unroll
        for (int ks = 0; ks < 4; ++ks) {
            short8 f;
            #pragma unroll
            for (int j = 0; j < 8; ++j) {
                const int c = ks * 32 + quad * 8 + j;
                f[j] = (short)f2b(qg[base + (long)c * N_ + query0 + qh * 16 + l15]);
            }
            qf[qh][ks] = f;
        }

    f32x4 acc[2][4];                  // [qh][ct]: 32q x 64c (channel-half h)
    #pragma unroll
    for (int qh = 0; qh < 2; ++qh)
        #pragma unroll
        for (int ct = 0; ct < 4; ++ct) acc[qh][ct] = (f32x4){0.f, 0.f, 0.f, 0.f};
    f32x4 accS[2];
    accS[0] = (f32x4){0.f, 0.f, 0.f, 0.f};
    accS[1] = (f32x4){0.f, 0.f, 0.f, 0.f};
    short8 ones;
    #pragma unroll
    for (int j = 0; j < 8; ++j) ones[j] = (short)0x3F80;   // bf16 1.0

    auto stageV = [&](int buf, int pair) {       // exactly 2 VMEM ops / lane
        const int mt = pair * 2 + g;
        char* lV = (char*)sm.s.V[buf][g];
        #pragma unroll
        for (int jj = 0; jj < 2; ++jj) {
            const int d  = sub * 2048 + jj * 1024;
            const int dv = d + lane * 16;
            const int c  = dv >> 6;
            gld_lds16((const char*)(vS + base + (long)c * N_ + mt * 32) + (dv & 63), lV + d);
        }
    };

    // ---- K direct global->reg: key = mt*32 + h*16 + l15, key&15 == l15 so
    // the baked-in kTs swizzle inverts with the same XOR as the LDS path ----
    const unsigned short* kp = kTs + base + (long)((g * 32 + h * 16 + l15) * C_);
    int ko[4];
    #pragma unroll
    for (int ks = 0; ks < 4; ++ks) ko[ks] = (((ks * 4 + quad) ^ l15) << 3);
    short8 kf[4];

    stageV(0, 0);
    #pragma unroll
    for (int ks = 0; ks < 4; ++ks) kf[ks] = *(const short8*)(const void*)(kp + ko[ks]);
    kp += 64 * C_;

    for (int i = 0; i < 64; ++i) {
        // ---- QK phase (registers only): P[32q][16k(h)] ----
        f32x4 sc[2];
        sc[0] = (f32x4){0.f, 0.f, 0.f, 0.f};
        sc[1] = (f32x4){0.f, 0.f, 0.f, 0.f};
        __builtin_amdgcn_s_setprio(1);
        #pragma unroll
        for (int qh = 0; qh < 2; ++qh)
            #pragma unroll
            for (int ks = 0; ks < 4; ++ks)
                sc[qh] = __builtin_amdgcn_mfma_f32_16x16x32_bf16(qf[qh][ks], kf[ks], sc[qh], 0, 0, 0);
        __builtin_amdgcn_s_setprio(0);

        // ---- prefetch kf(i+1): regs free, ~full iteration in flight ----
        if (i < 63) {
            #pragma unroll
            for (int ks = 0; ks < 4; ++ks) kf[ks] = *(const short8*)(const void*)(kp + ko[ks]);
            kp += 64 * C_;
        }

        // ---- softmax numerator -> P (iter-parity double buffer) ----
        short* Pw = sm.s.Pb[i & 1][g][wq];
        #pragma unroll
        for (int qh = 0; qh < 2; ++qh)
            #pragma unroll
            for (int r = 0; r < 4; ++r)
                Pw[(qh * 16 + quad * 4 + r) * 40 + h * 16 + l15] = (short)f2b(__expf(sc[qh][r]));

        // ---- single sync point: V(i) staged (vmcnt: kf(i+1) stays in
        // flight), own P writes drained, then barrier ----
        if (i < 63) asm volatile("s_waitcnt vmcnt(4)" ::: "memory");
        else        asm volatile("s_waitcnt vmcnt(0)" ::: "memory");
        asm volatile("s_waitcnt lgkmcnt(0)" ::: "memory");
        __builtin_amdgcn_s_barrier();
        __builtin_amdgcn_sched_barrier(0);

        // ---- V(i+1) stage: earliest legal point (all PV(i-1) reads of this
        // buffer completed before anyone passed B(i)) ----
        if (i < 63) stageV((i + 1) & 1, i + 1);

        // ---- PV phase: channel-half h, full 32-key P ----
        const short* Vb = sm.s.V[i & 1][g];
        const short8 pf0 = *(const short8*)(const void*)(Pw + (l15) * 40 + quad * 8);
        const short8 pf1 = *(const short8*)(const void*)(Pw + (16 + l15) * 40 + quad * 8);
        __builtin_amdgcn_s_setprio(1);
        if (h == 0) {                          // row-sums once per (g,wq)
            accS[0] = __builtin_amdgcn_mfma_f32_16x16x32_bf16(pf0, ones, accS[0], 0, 0, 0);
            accS[1] = __builtin_amdgcn_mfma_f32_16x16x32_bf16(pf1, ones, accS[1], 0, 0, 0);
        }
        #pragma unroll
        for (int ct = 0; ct < 4; ++ct) {
            const int ch = h * 64 + ct * 16 + l15;
            const short8 vf = *(const short8*)(const void*)(Vb + ch * 32 + ((quad ^ ((l15 >> 1) & 3)) << 3));
            acc[0][ct] = __builtin_amdgcn_mfma_f32_16x16x32_bf16(pf0, vf, acc[0][ct], 0, 0, 0);
            acc[1][ct] = __builtin_amdgcn_mfma_f32_16x16x32_bf16(pf1, vf, acc[1][ct], 0, 0, 0);
        }
        __builtin_amdgcn_s_setprio(0);
    }

    // ---- merge epilogue: Ot = O_g0 + O_g1; l via Ls; normalize + residual ----
    if (h == 0 && l15 == 0) {
        #pragma unroll
        for (int qh = 0; qh < 2; ++qh)
            #pragma unroll
            for (int r = 0; r < 4; ++r)
                Ls[g][wq][qh * 16 + quad * 4 + r] = accS[qh][r];
    }
    __syncthreads();                  // all PV reads done before Ot overlays LDS
    if (g == 0) {
        #pragma unroll
        for (int qh = 0; qh < 2; ++qh)
            #pragma unroll
            for (int ct = 0; ct < 4; ++ct)
                #pragma unroll
                for (int r = 0; r < 4; ++r)
                    sm.Ot[(32 * wq + qh * 16 + quad * 4 + r) * 130 + h * 64 + ct * 16 + l15] = acc[qh][ct][r];
    }
    __syncthreads();
    if (g == 1) {
        #pragma unroll
        for (int qh = 0; qh < 2; ++qh)
            #pragma unroll
            for (int ct = 0; ct < 4; ++ct)
                #pragma unroll
                for (int r = 0; r < 4; ++r)
                    sm.Ot[(32 * wq + qh * 16 + quad * 4 + r) * 130 + h * 64 + ct * 16 + l15] += acc[qh][ct][r];
    } else if (h == 0 && l15 == 0) {
        #pragma unroll
        for (int qh = 0; qh < 2; ++qh)
            #pragma unroll
            for (int r = 0; r < 4; ++r) {
                const int r32 = qh * 16 + quad * 4 + r;
                linvA[32 * wq + r32] = 1.0f / fmaxf(Ls[0][wq][r32] + Ls[1][wq][r32], 1e-20f);
            }
    }
    __syncthreads();

    const int c  = t >> 2;
    const int nh = (t & 3) * 16;
    const long gb = base + (long)c * N_ + n0 + nh;
    #pragma unroll
    for (int i = 0; i < 16; i += 4) {
        const float4 xs = *(const float4*)(const void*)(xg + gb + i);
        float4 rv;
        rv.x = sm.Ot[(nh + i + 0) * 130 + c] * linvA[nh + i + 0] + xs.x;
        rv.y = sm.Ot[(nh + i + 1) * 130 + c] * linvA[nh + i + 1] + xs.y;
        rv.z = sm.Ot[(nh + i + 2) * 130 + c] * linvA[nh + i + 2] + xs.z;
        rv.w = sm.Ot[(nh + i + 3) * 130 + c] * linvA[nh + i + 3] + xs.w;
        *(float4*)(void*)(out + gb + i) = rv;
    }
}

// ---------------------------------------------------------------------------
extern "C" void kernel_launch(void* const* d_in, const int* in_sizes, int n_in,
                              void* d_out, int out_size, void* d_ws, size_t ws_size,
                              hipStream_t stream) {
    const float* x  = (const float*)d_in[0];
    const float* Wq = (const float*)d_in[1];
    const float* bq = (const float*)d_in[2];
    const float* Wk = (const float*)d_in[3];
    const float* bk = (const float*)d_in[4];
    const float* Wv = (const float*)d_in[5];
    const float* bv = (const float*)d_in[6];
    float* out = (float*)d_out;

    const long BCN = (long)B_ * C_ * N_;                  // 4,194,304
    unsigned short* kTs = (unsigned short*)d_ws;          // [b][n][o'] bf16 swizzled
    unsigned short* vS  = kTs + BCN;                      // [b][o][n'] bf16 swizzled

    // q lives in d_out [b][c][n] fp32 (pre-scaled): each attn block reads only
    // its own query columns and overwrites exactly those columns at the end.
    qkv_mfma<<<1024, 256, 0, stream>>>(x, Wq, bq, Wk, bk, Wv, bv, out, kTs, vS);
    attn_mfma<<<B_ * (N_ / 64), 512, 0, stream>>>(out, kTs, vS, x, out);
}